// Round 2
// baseline (1031.991 us; speedup 1.0000x reference)
//
#include <hip/hip_runtime.h>
#include <stdint.h>

typedef uint32_t u32;
typedef uint64_t u64;

#define NLVL 4
#define NPRE 2000
#define NPOST 1000
#define KPAD 8192
#define TIE_CAP 4096

// ws layout (bytes)
#define OFF_SBITS 0u
#define OFF_HIST  (1u<<20)
#define OFF_CTRL  (2u<<20)
#define OFF_TIE   ((2u<<20) + (8u<<10))
#define OFF_CAND  ((2u<<20) + (128u<<10))
#define OFF_SHIFT ((2u<<20) + (256u<<10))
#define OFF_KEPT  ((2u<<20) + (384u<<10))

// ctrl word indices
#define C_CANDCNT 0
#define C_KEPTCNT 1
#define C_SEPMAX  2
#define C_P       4   // +lvl  (0xFFFFFFFF = deficient level)
#define C_RANK    8   // +lvl
#define C_T       16  // +lvl
#define C_NEED    20  // +lvl
#define C_TIECNT  24  // +lvl

// ---- monotone float<->u32 map for atomic max over floats ----
__device__ __forceinline__ u32 fmap(float f) {
  u32 u = __float_as_uint(f);
  return (u & 0x80000000u) ? ~u : (u | 0x80000000u);
}
__device__ __forceinline__ float funmap(u32 u) {
  u = (u & 0x80000000u) ? (u & 0x7FFFFFFFu) : ~u;
  return __uint_as_float(u);
}

// ---- replicate XLA-CPU GenerateVF32Exp (Cephes/Eigen-3.3 style) ----
// floor(fma(x, log2e, 0.5)); r = x - m*C1 - m*C2 (UNFUSED muls/subs);
// Horner degree-5 with FMA; scale by 2^m via exponent bits; max with input.
__device__ __forceinline__ float xla_expf(float x) {
  const float kLog2e = 1.44269504088896341f;
  const float kC1 = 0.693359375f;
  const float kC2 = -2.12194440e-4f;
  const float kP0 = 1.9875691500e-4f;
  const float kP1 = 1.3981999507e-3f;
  const float kP2 = 8.3334519073e-3f;
  const float kP3 = 4.1665795894e-2f;
  const float kP4 = 1.6666665459e-1f;
  const float kP5 = 5.0000001201e-1f;
  float xc = fminf(fmaxf(x, -88.3762626647949f), 88.3762626647950f);
  float fx = floorf(fmaf(xc, kLog2e, 0.5f));
  float tmp = __fmul_rn(kC1, fx);
  float z = __fmul_rn(kC2, fx);
  float r = __fsub_rn(xc, tmp);
  r = __fsub_rn(r, z);
  float r2 = __fmul_rn(r, r);
  float y = fmaf(r, kP0, kP1);
  y = fmaf(y, r, kP2);
  y = fmaf(y, r, kP3);
  y = fmaf(y, r, kP4);
  y = fmaf(y, r, kP5);
  y = fmaf(y, r2, r);
  y = __fadd_rn(y, 1.0f);
  int n = (int)fx;
  float two_n = __int_as_float((n + 127) << 23);
  return fmaxf(__fmul_rn(y, two_n), x);
}

// ---- IoU(a,b) > 0.7f with the reference's exact f32 op sequence ----
// box = (y1,x1,y2,x2) in .x,.y,.z,.w  (shifted coords)
__device__ __forceinline__ bool suppress(float4 a, float4 b) {
  float aa = __fmul_rn(__fsub_rn(a.z, a.x), __fsub_rn(a.w, a.y));
  float ab = __fmul_rn(__fsub_rn(b.z, b.x), __fsub_rn(b.w, b.y));
  float lty = fmaxf(a.x, b.x);
  float ltx = fmaxf(a.y, b.y);
  float rby = fminf(a.z, b.z);
  float rbx = fminf(a.w, b.w);
  float why = fmaxf(__fsub_rn(rby, lty), 0.0f);
  float whx = fmaxf(__fsub_rn(rbx, ltx), 0.0f);
  float inter = __fmul_rn(why, whx);
  float uni = __fsub_rn(__fadd_rn(aa, ab), inter);
  float iou = inter / fmaxf(uni, 1e-9f);
  return iou > 0.7f;
}

__device__ __forceinline__ u64 makekey(u32 sbits, u32 lvl, u32 idx) {
  // ascending key == (score desc, level asc, index asc); total order (idx unique)
  return ((u64)(0x7FFFFFFFu - sbits) << 20) | ((u64)lvl << 18) | (u64)idx;
}

// 1) softmax score + hi16 histogram per level
__global__ void k_score_hist(const float2* __restrict__ logits, const int* __restrict__ levels,
                             u32* __restrict__ sbits, u32* __restrict__ hist, int n) {
  int i = blockIdx.x * blockDim.x + threadIdx.x;
  if (i >= n) return;
  float2 lg = logits[i];
  float m = fmaxf(lg.x, lg.y);
  float e0 = xla_expf(__fsub_rn(lg.x, m));
  float e1 = xla_expf(__fsub_rn(lg.y, m));
  float s = e1 / __fadd_rn(e0, e1);   // IEEE div
  u32 b = __float_as_uint(s);
  sbits[i] = b;
  int lv = levels[i];
  atomicAdd(&hist[lv * 65536 + (int)(b >> 16)], 1u);
}

// 2) per-level descending scan of hi16 histogram -> bin containing rank NPRE
__global__ void k_scan_hi(const u32* __restrict__ hist, u32* __restrict__ ctrl) {
  int lvl = blockIdx.x;
  int tid = threadIdx.x;
  const u32* h = hist + lvl * 65536;
  __shared__ u32 part[256];
  u32 s = 0;
  int base = tid * 256;
  for (int b = 0; b < 256; ++b) s += h[base + b];
  part[tid] = s;
  __syncthreads();
  if (tid == 0) {
    const u32 target = NPRE;
    u32 cum = 0, before = 0; int seg = -1;
    for (int t = 255; t >= 0; --t) {
      if (seg < 0 && cum + part[t] >= target) { seg = t; before = cum; }
      cum += part[t];
    }
    if (cum < target) {           // deficient level: select everything (score>0)
      ctrl[C_P + lvl] = 0xFFFFFFFFu;
      ctrl[C_T + lvl] = 0u;
      ctrl[C_NEED + lvl] = 0u;
    } else {
      u32 c = before; u32 bin = 0;
      for (int b = seg * 256 + 255; b >= seg * 256; --b) {
        u32 hb = h[b];
        if (c + hb >= target) { bin = (u32)b; break; }
        c += hb;
      }
      ctrl[C_P + lvl] = bin;
      ctrl[C_RANK + lvl] = target - c;   // >=1 elements needed inside bin
    }
  }
}

// 3) lo16 histogram restricted to hi16 == P
__global__ void k_hist_lo(const u32* __restrict__ sbits, const int* __restrict__ levels,
                          const u32* __restrict__ ctrl, u32* __restrict__ hist, int n) {
  int i = blockIdx.x * blockDim.x + threadIdx.x;
  if (i >= n) return;
  u32 b = sbits[i];
  int lv = levels[i];
  if ((b >> 16) == ctrl[C_P + lv])
    atomicAdd(&hist[lv * 65536 + (int)(b & 0xFFFFu)], 1u);
}

// 4) per-level descending scan of lo16 -> exact 32-bit threshold T and tie need
__global__ void k_scan_lo(const u32* __restrict__ hist, u32* __restrict__ ctrl) {
  int lvl = blockIdx.x;
  u32 P = ctrl[C_P + lvl];
  if (P == 0xFFFFFFFFu) return;   // uniform: deficient already handled
  int tid = threadIdx.x;
  const u32* h = hist + lvl * 65536;
  __shared__ u32 part[256];
  u32 s = 0;
  int base = tid * 256;
  for (int b = 0; b < 256; ++b) s += h[base + b];
  part[tid] = s;
  __syncthreads();
  if (tid == 0) {
    u32 target = ctrl[C_RANK + lvl];
    u32 cum = 0, before = 0; int seg = -1;
    for (int t = 255; t >= 0; --t) {
      if (seg < 0 && cum + part[t] >= target) { seg = t; before = cum; }
      cum += part[t];
    }
    u32 c = before; u32 bin = 0;
    for (int b = seg * 256 + 255; b >= seg * 256; --b) {
      u32 hb = h[b];
      if (c + hb >= target) { bin = (u32)b; break; }
      c += hb;
    }
    ctrl[C_T + lvl] = (P << 16) | bin;
    ctrl[C_NEED + lvl] = target - c;    // take this many smallest-index among ==T
  }
}

// 5) compact: strictly-above-threshold -> cand keys; ==T -> tie buffer; sep max
__global__ void k_compact(const u32* __restrict__ sbits, const int* __restrict__ levels,
                          const float4* __restrict__ rois, u32* __restrict__ ctrl,
                          u64* __restrict__ cand, u32* __restrict__ tie, int n) {
  int i = blockIdx.x * blockDim.x + threadIdx.x;
  if (i >= n) return;
  u32 b = sbits[i];
  int lv = levels[i];
  u32 T = ctrl[C_T + lv];
  if (b > T) {
    u32 p = atomicAdd(&ctrl[C_CANDCNT], 1u);
    if (p < (u32)KPAD) cand[p] = makekey(b, (u32)lv, (u32)i);
    float4 r = rois[i];
    u32 mx = max(max(fmap(r.x), fmap(r.y)), max(fmap(r.z), fmap(r.w)));
    atomicMax(&ctrl[C_SEPMAX], mx);
  } else if (b == T) {
    u32 t = atomicAdd(&ctrl[C_TIECNT + lv], 1u);
    if (t < TIE_CAP) tie[lv * TIE_CAP + t] = (u32)i;
  }
}

// 6) resolve threshold ties: smallest indices first (top_k is stable)
__global__ void k_ties(const float4* __restrict__ rois, u32* __restrict__ ctrl,
                       u64* __restrict__ cand, const u32* __restrict__ tie) {
  int lvl = blockIdx.x;
  int tid = threadIdx.x;
  u32 need = ctrl[C_NEED + lvl];
  if (need == 0) return;            // uniform per block
  u32 n = min(ctrl[C_TIECNT + lvl], (u32)TIE_CAP);
  __shared__ u32 buf[TIE_CAP];
  for (int t = tid; t < TIE_CAP; t += 256)
    buf[t] = (t < (int)n) ? tie[lvl * TIE_CAP + t] : 0xFFFFFFFFu;
  __syncthreads();
  for (u32 k = 2; k <= TIE_CAP; k <<= 1) {
    for (u32 j = k >> 1; j > 0; j >>= 1) {
      for (u32 p = tid; p < TIE_CAP; p += 256) {
        u32 q = p ^ j;
        if (q > p) {
          u32 a = buf[p], b = buf[q];
          bool desc = (p & k) != 0;
          if (desc ? (a < b) : (a > b)) { buf[p] = b; buf[q] = a; }
        }
      }
      __syncthreads();
    }
  }
  __shared__ u32 basep;
  if (tid == 0) basep = atomicAdd(&ctrl[C_CANDCNT], need);
  __syncthreads();
  u32 T = ctrl[C_T + lvl];
  for (u32 t = tid; t < need; t += 256) {
    u32 idx = buf[t];
    if (basep + t < (u32)KPAD) cand[basep + t] = makekey(T, (u32)lvl, idx);
    float4 r = rois[idx];
    u32 mx = max(max(fmap(r.x), fmap(r.y)), max(fmap(r.z), fmap(r.w)));
    atomicMax(&ctrl[C_SEPMAX], mx);
  }
}

// 7) bitonic sort of 8192 u64 keys in LDS -> global NMS order (total order)
__global__ __launch_bounds__(1024) void k_sort(u64* __restrict__ cand, const u32* __restrict__ ctrl) {
  __shared__ u64 a[KPAD];
  int tid = threadIdx.x;
  u32 total = min(ctrl[C_CANDCNT], (u32)KPAD);
  for (int p = tid; p < KPAD; p += 1024) a[p] = (p < (int)total) ? cand[p] : ~0ull;
  __syncthreads();
  for (u32 k = 2; k <= KPAD; k <<= 1) {
    for (u32 j = k >> 1; j > 0; j >>= 1) {
      for (u32 p = tid; p < (u32)KPAD; p += 1024) {
        u32 q = p ^ j;
        if (q > p) {
          u64 x = a[p], y = a[q];
          bool desc = (p & k) != 0;
          if (desc ? (x < y) : (x > y)) { a[p] = y; a[q] = x; }
        }
      }
      __syncthreads();
    }
  }
  for (int p = tid; p < KPAD; p += 1024) cand[p] = a[p];
}

// 8) level-shifted boxes in sorted order (exact: sh = fl(lvl*sep); coord+sh)
__global__ void k_shift(const u64* __restrict__ cand, const float4* __restrict__ rois,
                        const u32* __restrict__ ctrl, float4* __restrict__ shifted) {
  int k = blockIdx.x * blockDim.x + threadIdx.x;
  if (k >= KPAD) return;
  u32 total = min(ctrl[C_CANDCNT], (u32)KPAD);
  float sep = __fadd_rn(funmap(ctrl[C_SEPMAX]), 1.0f);
  float4 o = make_float4(0.f, 0.f, 0.f, 0.f);
  if (k < (int)total) {
    u64 a = cand[k];
    u32 idx = (u32)(a & 0x3FFFFu);
    u32 lvl = (u32)((a >> 18) & 3u);
    float4 r = rois[idx];
    float sh = __fmul_rn((float)lvl, sep);
    o.x = __fadd_rn(r.x, sh);
    o.y = __fadd_rn(r.y, sh);
    o.z = __fadd_rn(r.z, sh);
    o.w = __fadd_rn(r.w, sh);
  }
  shifted[k] = o;
}

// 9) sequential greedy NMS, kept boxes in LDS, early exit at NPOST kept
__global__ __launch_bounds__(1024) void k_nms(const float4* __restrict__ shifted,
                                              u32* __restrict__ ctrl, u32* __restrict__ keptpos) {
  __shared__ float4 kbox[NPOST];
  __shared__ u32 wflag[16];
  int tid = threadIdx.x;
  u32 total = min(ctrl[C_CANDCNT], (u32)KPAD);
  int n = 0;
  for (u32 i = 0; i < total; ++i) {
    float4 cur = shifted[i];
    bool sup = false;
    if (tid < n) sup = suppress(kbox[tid], cur);
    int any = __any(sup);
    if ((tid & 63) == 0) wflag[tid >> 6] = (u32)any;
    __syncthreads();
    u32 f = 0;
#pragma unroll
    for (int w = 0; w < 16; ++w) f |= wflag[w];
    if (!f) {
      if (tid == 0) { kbox[n] = cur; keptpos[n] = i; }
      ++n;                       // uniform across all threads
    }
    __syncthreads();
    if (n >= NPOST) break;
  }
  if (tid == 0) ctrl[C_KEPTCNT] = (u32)n;
}

// 10) gather outputs; small-box filter; write everything as f32
__global__ void k_out(const u64* __restrict__ cand, const u32* __restrict__ keptpos,
                      const u32* __restrict__ ctrl, const float2* __restrict__ logits,
                      const float4* __restrict__ rois, float* __restrict__ out) {
  int r = blockIdx.x * blockDim.x + threadIdx.x;
  if (r >= NPOST) return;
  u32 kn = ctrl[C_KEPTCNT];
  float l0 = 0.f, l1 = 0.f, r0 = 0.f, r1 = 0.f, r2 = 0.f, r3 = 0.f;
  float lvf = -1.0f, vf = 0.0f;
  if (r < (int)kn) {
    u32 pos = keptpos[r];
    u64 a = cand[pos];
    u32 idx = (u32)(a & 0x3FFFFu);
    u32 lvl = (u32)((a >> 18) & 3u);
    float4 rb = rois[idx];
    float hs = __fsub_rn(rb.z, rb.x);
    float wsz = __fsub_rn(rb.w, rb.y);
    if (hs >= 1.0f && wsz >= 1.0f) {
      float2 lg = logits[idx];
      l0 = lg.x; l1 = lg.y;
      r0 = rb.x; r1 = rb.y; r2 = rb.z; r3 = rb.w;
      lvf = (float)lvl; vf = 1.0f;
    }
  }
  out[2 * r] = l0;
  out[2 * r + 1] = l1;
  out[2 * NPOST + 4 * r + 0] = r0;
  out[2 * NPOST + 4 * r + 1] = r1;
  out[2 * NPOST + 4 * r + 2] = r2;
  out[2 * NPOST + 4 * r + 3] = r3;
  out[6 * NPOST + r] = lvf;
  out[7 * NPOST + r] = vf;
}

extern "C" void kernel_launch(void* const* d_in, const int* in_sizes, int n_in,
                              void* d_out, int out_size, void* d_ws, size_t ws_size,
                              hipStream_t stream) {
  const float* logits = (const float*)d_in[0];
  const float* rois = (const float*)d_in[1];
  const int* levels = (const int*)d_in[2];
  int N = in_sizes[2];

  char* ws = (char*)d_ws;
  u32* sbits = (u32*)(ws + OFF_SBITS);
  u32* hist = (u32*)(ws + OFF_HIST);
  u32* ctrl = (u32*)(ws + OFF_CTRL);
  u32* tie = (u32*)(ws + OFF_TIE);
  u64* cand = (u64*)(ws + OFF_CAND);
  float4* shifted = (float4*)(ws + OFF_SHIFT);
  u32* keptpos = (u32*)(ws + OFF_KEPT);

  hipMemsetAsync(ctrl, 0, 4096, stream);
  hipMemsetAsync(hist, 0, NLVL * 65536 * sizeof(u32), stream);

  int nb = (N + 255) / 256;
  k_score_hist<<<nb, 256, 0, stream>>>((const float2*)logits, levels, sbits, hist, N);
  k_scan_hi<<<NLVL, 256, 0, stream>>>(hist, ctrl);
  hipMemsetAsync(hist, 0, NLVL * 65536 * sizeof(u32), stream);
  k_hist_lo<<<nb, 256, 0, stream>>>(sbits, levels, ctrl, hist, N);
  k_scan_lo<<<NLVL, 256, 0, stream>>>(hist, ctrl);
  k_compact<<<nb, 256, 0, stream>>>(sbits, levels, (const float4*)rois, ctrl, cand, tie, N);
  k_ties<<<NLVL, 256, 0, stream>>>((const float4*)rois, ctrl, cand, tie);
  k_sort<<<1, 1024, 0, stream>>>(cand, ctrl);
  k_shift<<<(KPAD + 255) / 256, 256, 0, stream>>>(cand, (const float4*)rois, ctrl, shifted);
  k_nms<<<1, 1024, 0, stream>>>(shifted, ctrl, keptpos);
  k_out<<<(NPOST + 255) / 256, 256, 0, stream>>>(cand, keptpos, ctrl, (const float2*)logits,
                                                 (const float4*)rois, (float*)d_out);
}

// Round 3
// 699.832 us; speedup vs baseline: 1.4746x; 1.4746x over previous
//
#include <hip/hip_runtime.h>
#include <stdint.h>

typedef uint32_t u32;
typedef uint64_t u64;

#define NLVL 4
#define NPRE 2000
#define NPOST 1000
#define KPAD 8192
#define TIE_CAP 4096
#define NCHUNK 128          // row stride in u64 words (125 used, padded to 128)

// ws layout (bytes)
#define OFF_SBITS 0u                       // 1 MB  (250K u32)
#define OFF_HIST  (1u<<20)                 // 1 MB  (4*64K u32)
#define OFF_CTRL  (2u<<20)                 // 64 KB
#define OFF_TIE   ((2u<<20) + (64u<<10))   // 64 KB
#define OFF_CAND  ((2u<<20) + (128u<<10))  // 64 KB
#define OFF_SHIFT ((2u<<20) + (192u<<10))  // 128 KB
#define OFF_KEPT  ((2u<<20) + (320u<<10))  // 64 KB
#define OFF_MASK  (3u<<20)                 // 8 MB  (8192 rows * 128 u64)
#define WS_NEED   ((size_t)(3u<<20) + (size_t)KPAD * NCHUNK * 8u)

// ctrl word indices
#define C_CANDCNT 0
#define C_KEPTCNT 1
#define C_SEPMAX  2
#define C_P       4   // +lvl  (0xFFFFFFFF = deficient level)
#define C_RANK    8   // +lvl
#define C_T       16  // +lvl
#define C_NEED    20  // +lvl
#define C_TIECNT  24  // +lvl

// ---- monotone float<->u32 map for atomic max over floats ----
__device__ __forceinline__ u32 fmap(float f) {
  u32 u = __float_as_uint(f);
  return (u & 0x80000000u) ? ~u : (u | 0x80000000u);
}
__device__ __forceinline__ float funmap(u32 u) {
  u = (u & 0x80000000u) ? (u & 0x7FFFFFFFu) : ~u;
  return __uint_as_float(u);
}

// ---- replicate XLA-CPU GenerateVF32Exp (Cephes/Eigen-3.3 style) ----
__device__ __forceinline__ float xla_expf(float x) {
  const float kLog2e = 1.44269504088896341f;
  const float kC1 = 0.693359375f;
  const float kC2 = -2.12194440e-4f;
  const float kP0 = 1.9875691500e-4f;
  const float kP1 = 1.3981999507e-3f;
  const float kP2 = 8.3334519073e-3f;
  const float kP3 = 4.1665795894e-2f;
  const float kP4 = 1.6666665459e-1f;
  const float kP5 = 5.0000001201e-1f;
  float xc = fminf(fmaxf(x, -88.3762626647949f), 88.3762626647950f);
  float fx = floorf(fmaf(xc, kLog2e, 0.5f));
  float tmp = __fmul_rn(kC1, fx);
  float z = __fmul_rn(kC2, fx);
  float r = __fsub_rn(xc, tmp);
  r = __fsub_rn(r, z);
  float r2 = __fmul_rn(r, r);
  float y = fmaf(r, kP0, kP1);
  y = fmaf(y, r, kP2);
  y = fmaf(y, r, kP3);
  y = fmaf(y, r, kP4);
  y = fmaf(y, r, kP5);
  y = fmaf(y, r2, r);
  y = __fadd_rn(y, 1.0f);
  int n = (int)fx;
  float two_n = __int_as_float((n + 127) << 23);
  return fmaxf(__fmul_rn(y, two_n), x);
}

// ---- IoU(a,b) > 0.7f with the reference's exact f32 op sequence (symmetric) ----
__device__ __forceinline__ bool suppress(float4 a, float4 b) {
  float aa = __fmul_rn(__fsub_rn(a.z, a.x), __fsub_rn(a.w, a.y));
  float ab = __fmul_rn(__fsub_rn(b.z, b.x), __fsub_rn(b.w, b.y));
  float lty = fmaxf(a.x, b.x);
  float ltx = fmaxf(a.y, b.y);
  float rby = fminf(a.z, b.z);
  float rbx = fminf(a.w, b.w);
  float why = fmaxf(__fsub_rn(rby, lty), 0.0f);
  float whx = fmaxf(__fsub_rn(rbx, ltx), 0.0f);
  float inter = __fmul_rn(why, whx);
  float uni = __fsub_rn(__fadd_rn(aa, ab), inter);
  float iou = inter / fmaxf(uni, 1e-9f);
  return iou > 0.7f;
}

__device__ __forceinline__ u64 makekey(u32 sbits, u32 lvl, u32 idx) {
  // ascending key == (score desc, level asc, index asc); total order (idx unique)
  return ((u64)(0x7FFFFFFFu - sbits) << 20) | ((u64)lvl << 18) | (u64)idx;
}

// 1) softmax score + hi16 histogram per level
__global__ void k_score_hist(const float2* __restrict__ logits, const int* __restrict__ levels,
                             u32* __restrict__ sbits, u32* __restrict__ hist, int n) {
  int i = blockIdx.x * blockDim.x + threadIdx.x;
  if (i >= n) return;
  float2 lg = logits[i];
  float m = fmaxf(lg.x, lg.y);
  float e0 = xla_expf(__fsub_rn(lg.x, m));
  float e1 = xla_expf(__fsub_rn(lg.y, m));
  float s = e1 / __fadd_rn(e0, e1);   // IEEE div
  u32 b = __float_as_uint(s);
  sbits[i] = b;
  int lv = levels[i];
  atomicAdd(&hist[lv * 65536 + (int)(b >> 16)], 1u);
}

// 2) per-level descending scan of hi16 histogram -> bin containing rank NPRE
__global__ void k_scan_hi(const u32* __restrict__ hist, u32* __restrict__ ctrl) {
  int lvl = blockIdx.x;
  int tid = threadIdx.x;
  const u32* h = hist + lvl * 65536;
  __shared__ u32 part[256];
  u32 s = 0;
  int base = tid * 256;
  for (int b = 0; b < 256; ++b) s += h[base + b];
  part[tid] = s;
  __syncthreads();
  if (tid == 0) {
    const u32 target = NPRE;
    u32 cum = 0, before = 0; int seg = -1;
    for (int t = 255; t >= 0; --t) {
      if (seg < 0 && cum + part[t] >= target) { seg = t; before = cum; }
      cum += part[t];
    }
    if (cum < target) {           // deficient level: select everything (score>0)
      ctrl[C_P + lvl] = 0xFFFFFFFFu;
      ctrl[C_T + lvl] = 0u;
      ctrl[C_NEED + lvl] = 0u;
    } else {
      u32 c = before; u32 bin = 0;
      for (int b = seg * 256 + 255; b >= seg * 256; --b) {
        u32 hb = h[b];
        if (c + hb >= target) { bin = (u32)b; break; }
        c += hb;
      }
      ctrl[C_P + lvl] = bin;
      ctrl[C_RANK + lvl] = target - c;   // >=1 elements needed inside bin
    }
  }
}

// 3) lo16 histogram restricted to hi16 == P
__global__ void k_hist_lo(const u32* __restrict__ sbits, const int* __restrict__ levels,
                          const u32* __restrict__ ctrl, u32* __restrict__ hist, int n) {
  int i = blockIdx.x * blockDim.x + threadIdx.x;
  if (i >= n) return;
  u32 b = sbits[i];
  int lv = levels[i];
  if ((b >> 16) == ctrl[C_P + lv])
    atomicAdd(&hist[lv * 65536 + (int)(b & 0xFFFFu)], 1u);
}

// 4) per-level descending scan of lo16 -> exact 32-bit threshold T and tie need
__global__ void k_scan_lo(const u32* __restrict__ hist, u32* __restrict__ ctrl) {
  int lvl = blockIdx.x;
  u32 P = ctrl[C_P + lvl];
  if (P == 0xFFFFFFFFu) return;   // uniform: deficient already handled
  int tid = threadIdx.x;
  const u32* h = hist + lvl * 65536;
  __shared__ u32 part[256];
  u32 s = 0;
  int base = tid * 256;
  for (int b = 0; b < 256; ++b) s += h[base + b];
  part[tid] = s;
  __syncthreads();
  if (tid == 0) {
    u32 target = ctrl[C_RANK + lvl];
    u32 cum = 0, before = 0; int seg = -1;
    for (int t = 255; t >= 0; --t) {
      if (seg < 0 && cum + part[t] >= target) { seg = t; before = cum; }
      cum += part[t];
    }
    u32 c = before; u32 bin = 0;
    for (int b = seg * 256 + 255; b >= seg * 256; --b) {
      u32 hb = h[b];
      if (c + hb >= target) { bin = (u32)b; break; }
      c += hb;
    }
    ctrl[C_T + lvl] = (P << 16) | bin;
    ctrl[C_NEED + lvl] = target - c;    // take this many smallest-index among ==T
  }
}

// 5) compact: strictly-above-threshold -> cand keys; ==T -> tie buffer; sep max
__global__ void k_compact(const u32* __restrict__ sbits, const int* __restrict__ levels,
                          const float4* __restrict__ rois, u32* __restrict__ ctrl,
                          u64* __restrict__ cand, u32* __restrict__ tie, int n) {
  int i = blockIdx.x * blockDim.x + threadIdx.x;
  if (i >= n) return;
  u32 b = sbits[i];
  int lv = levels[i];
  u32 T = ctrl[C_T + lv];
  if (b > T) {
    u32 p = atomicAdd(&ctrl[C_CANDCNT], 1u);
    if (p < (u32)KPAD) cand[p] = makekey(b, (u32)lv, (u32)i);
    float4 r = rois[i];
    u32 mx = max(max(fmap(r.x), fmap(r.y)), max(fmap(r.z), fmap(r.w)));
    atomicMax(&ctrl[C_SEPMAX], mx);
  } else if (b == T) {
    u32 t = atomicAdd(&ctrl[C_TIECNT + lv], 1u);
    if (t < TIE_CAP) tie[lv * TIE_CAP + t] = (u32)i;
  }
}

// 6) resolve threshold ties: smallest indices first (top_k is stable)
__global__ void k_ties(const float4* __restrict__ rois, u32* __restrict__ ctrl,
                       u64* __restrict__ cand, const u32* __restrict__ tie) {
  int lvl = blockIdx.x;
  int tid = threadIdx.x;
  u32 need = ctrl[C_NEED + lvl];
  if (need == 0) return;            // uniform per block
  u32 n = min(ctrl[C_TIECNT + lvl], (u32)TIE_CAP);
  __shared__ u32 buf[TIE_CAP];
  for (int t = tid; t < TIE_CAP; t += 256)
    buf[t] = (t < (int)n) ? tie[lvl * TIE_CAP + t] : 0xFFFFFFFFu;
  __syncthreads();
  for (u32 k = 2; k <= TIE_CAP; k <<= 1) {
    for (u32 j = k >> 1; j > 0; j >>= 1) {
      for (u32 p = tid; p < TIE_CAP; p += 256) {
        u32 q = p ^ j;
        if (q > p) {
          u32 a = buf[p], b = buf[q];
          bool desc = (p & k) != 0;
          if (desc ? (a < b) : (a > b)) { buf[p] = b; buf[q] = a; }
        }
      }
      __syncthreads();
    }
  }
  __shared__ u32 basep;
  if (tid == 0) basep = atomicAdd(&ctrl[C_CANDCNT], need);
  __syncthreads();
  u32 T = ctrl[C_T + lvl];
  for (u32 t = tid; t < need; t += 256) {
    u32 idx = buf[t];
    if (basep + t < (u32)KPAD) cand[basep + t] = makekey(T, (u32)lvl, idx);
    float4 r = rois[idx];
    u32 mx = max(max(fmap(r.x), fmap(r.y)), max(fmap(r.z), fmap(r.w)));
    atomicMax(&ctrl[C_SEPMAX], mx);
  }
}

// 7) bitonic sort of 8192 u64 keys in LDS -> global NMS order (total order)
__global__ __launch_bounds__(1024) void k_sort(u64* __restrict__ cand, const u32* __restrict__ ctrl) {
  __shared__ u64 a[KPAD];
  int tid = threadIdx.x;
  u32 total = min(ctrl[C_CANDCNT], (u32)KPAD);
  for (int p = tid; p < KPAD; p += 1024) a[p] = (p < (int)total) ? cand[p] : ~0ull;
  __syncthreads();
  for (u32 k = 2; k <= KPAD; k <<= 1) {
    for (u32 j = k >> 1; j > 0; j >>= 1) {
      for (u32 p = tid; p < (u32)KPAD; p += 1024) {
        u32 q = p ^ j;
        if (q > p) {
          u64 x = a[p], y = a[q];
          bool desc = (p & k) != 0;
          if (desc ? (x < y) : (x > y)) { a[p] = y; a[q] = x; }
        }
      }
      __syncthreads();
    }
  }
  for (int p = tid; p < KPAD; p += 1024) cand[p] = a[p];
}

// 8) level-shifted boxes in sorted order (exact: sh = fl(lvl*sep); coord+sh)
__global__ void k_shift(const u64* __restrict__ cand, const float4* __restrict__ rois,
                        const u32* __restrict__ ctrl, float4* __restrict__ shifted) {
  int k = blockIdx.x * blockDim.x + threadIdx.x;
  if (k >= KPAD) return;
  u32 total = min(ctrl[C_CANDCNT], (u32)KPAD);
  float sep = __fadd_rn(funmap(ctrl[C_SEPMAX]), 1.0f);
  float4 o = make_float4(0.f, 0.f, 0.f, 0.f);
  if (k < (int)total) {
    u64 a = cand[k];
    u32 idx = (u32)(a & 0x3FFFFu);
    u32 lvl = (u32)((a >> 18) & 3u);
    float4 r = rois[idx];
    float sh = __fmul_rn((float)lvl, sep);
    o.x = __fadd_rn(r.x, sh);
    o.y = __fadd_rn(r.y, sh);
    o.z = __fadd_rn(r.z, sh);
    o.w = __fadd_rn(r.w, sh);
  }
  shifted[k] = o;
}

// 9a) build suppression bitmask: mask[i][cb] bit j = (iou(i, cb*64+j)>0.7 && cb*64+j > i)
//     grid (125 col-chunks, 125 row-chunks), 64 threads = one row each.
__global__ __launch_bounds__(64) void k_build(const float4* __restrict__ shifted,
                                              u64* __restrict__ mask) {
  u32 cb = blockIdx.x, rb = blockIdx.y;
  if (cb < rb) return;                 // lower triangle never read meaningfully
  int t = threadIdx.x;
  __shared__ float4 cbox[64];
  cbox[t] = shifted[cb * 64 + t];
  u32 i = rb * 64 + t;
  float4 bi = shifted[i];
  __syncthreads();
  u64 bits = 0;
  for (int j = 0; j < 64; ++j) {
    u32 jg = cb * 64 + j;
    if (jg > i && suppress(bi, cbox[j])) bits |= (1ull << j);
  }
  mask[(u64)i * NCHUNK + cb] = bits;
}

// 9b) single-wave greedy scan over bitmask; zero LDS, zero barriers.
//     Lane t owns "removed" words 2t, 2t+1. Per 64-chunk: broadcast removed word,
//     resolve intra-chunk greedy via shfl of lane-resident diag words, then OR
//     kept rows' full masks (8 rows per batched L3 round-trip).
__global__ __launch_bounds__(64) void k_scan(const u64* __restrict__ mask,
                                             u32* __restrict__ ctrl,
                                             u32* __restrict__ keptpos) {
  int t = threadIdx.x;
  u32 total = min(ctrl[C_CANDCNT], (u32)KPAD);
  u32 chunks = (total + 63) >> 6;
  u64 r0 = 0, r1 = 0;
  u32 kept = 0;
  // prefetch diag word for chunk 0
  u64 intra = (chunks > 0) ? mask[(u64)t * NCHUNK + 0] : 0;
  for (u32 c = 0; c < chunks; ++c) {
    u64 rr = (c & 1) ? r1 : r0;
    u64 remc = (u64)__shfl((long long)rr, (int)(c >> 1));
    u64 w = ~remc;
    u32 rem2 = total - c * 64;
    if (rem2 < 64) w &= ((1ull << rem2) - 1ull);
    u64 myintra = intra;
    if (c + 1 < chunks) intra = mask[((u64)(c + 1) * 64 + t) * NCHUNK + (c + 1)];
    // intra-chunk greedy resolution (uniform across lanes)
    u64 keptbits = 0;
    while (w && kept < NPOST) {
      u32 s = (u32)__builtin_ctzll(w);
      keptbits |= (1ull << s);
      if (t == 0) keptpos[kept] = c * 64 + s;
      ++kept;
      u64 row = (u64)__shfl((long long)myintra, (int)s);
      w &= ~row;
      w &= ~(1ull << s);
    }
    if (kept >= NPOST) break;
    // OR kept rows' masks into removed registers, 8 rows per batch
    u64 kb = keptbits;
    const u64* bp = mask + (u64)c * 64 * NCHUNK + (u64)(2 * t);
    while (kb) {
      u32 sA = (u32)__builtin_ctzll(kb); kb &= kb - 1;
      u32 sB = sA, sC = sA, sD = sA, sE = sA, sF = sA, sG = sA, sH = sA;
      if (kb) { sB = (u32)__builtin_ctzll(kb); kb &= kb - 1;
      if (kb) { sC = (u32)__builtin_ctzll(kb); kb &= kb - 1;
      if (kb) { sD = (u32)__builtin_ctzll(kb); kb &= kb - 1;
      if (kb) { sE = (u32)__builtin_ctzll(kb); kb &= kb - 1;
      if (kb) { sF = (u32)__builtin_ctzll(kb); kb &= kb - 1;
      if (kb) { sG = (u32)__builtin_ctzll(kb); kb &= kb - 1;
      if (kb) { sH = (u32)__builtin_ctzll(kb); kb &= kb - 1; }}}}}}}
      ulonglong2 gA = *(const ulonglong2*)(bp + (u64)sA * NCHUNK);
      ulonglong2 gB = *(const ulonglong2*)(bp + (u64)sB * NCHUNK);
      ulonglong2 gC = *(const ulonglong2*)(bp + (u64)sC * NCHUNK);
      ulonglong2 gD = *(const ulonglong2*)(bp + (u64)sD * NCHUNK);
      ulonglong2 gE = *(const ulonglong2*)(bp + (u64)sE * NCHUNK);
      ulonglong2 gF = *(const ulonglong2*)(bp + (u64)sF * NCHUNK);
      ulonglong2 gG = *(const ulonglong2*)(bp + (u64)sG * NCHUNK);
      ulonglong2 gH = *(const ulonglong2*)(bp + (u64)sH * NCHUNK);
      r0 |= gA.x | gB.x | gC.x | gD.x | gE.x | gF.x | gG.x | gH.x;
      r1 |= gA.y | gB.y | gC.y | gD.y | gE.y | gF.y | gG.y | gH.y;
    }
  }
  if (t == 0) ctrl[C_KEPTCNT] = kept;
}

// 9-fallback) sequential greedy NMS (used only if ws too small for the mask)
__global__ __launch_bounds__(1024) void k_nms(const float4* __restrict__ shifted,
                                              u32* __restrict__ ctrl, u32* __restrict__ keptpos) {
  __shared__ float4 kbox[NPOST];
  __shared__ u32 wflag[16];
  int tid = threadIdx.x;
  u32 total = min(ctrl[C_CANDCNT], (u32)KPAD);
  int n = 0;
  for (u32 i = 0; i < total; ++i) {
    float4 cur = shifted[i];
    bool sup = false;
    if (tid < n) sup = suppress(kbox[tid], cur);
    int any = __any(sup);
    if ((tid & 63) == 0) wflag[tid >> 6] = (u32)any;
    __syncthreads();
    u32 f = 0;
#pragma unroll
    for (int w = 0; w < 16; ++w) f |= wflag[w];
    if (!f) {
      if (tid == 0) { kbox[n] = cur; keptpos[n] = i; }
      ++n;
    }
    __syncthreads();
    if (n >= NPOST) break;
  }
  if (tid == 0) ctrl[C_KEPTCNT] = (u32)n;
}

// 10) gather outputs; small-box filter; write everything as f32
__global__ void k_out(const u64* __restrict__ cand, const u32* __restrict__ keptpos,
                      const u32* __restrict__ ctrl, const float2* __restrict__ logits,
                      const float4* __restrict__ rois, float* __restrict__ out) {
  int r = blockIdx.x * blockDim.x + threadIdx.x;
  if (r >= NPOST) return;
  u32 kn = ctrl[C_KEPTCNT];
  float l0 = 0.f, l1 = 0.f, r0 = 0.f, r1 = 0.f, r2 = 0.f, r3 = 0.f;
  float lvf = -1.0f, vf = 0.0f;
  if (r < (int)kn) {
    u32 pos = keptpos[r];
    u64 a = cand[pos];
    u32 idx = (u32)(a & 0x3FFFFu);
    u32 lvl = (u32)((a >> 18) & 3u);
    float4 rb = rois[idx];
    float hs = __fsub_rn(rb.z, rb.x);
    float wsz = __fsub_rn(rb.w, rb.y);
    if (hs >= 1.0f && wsz >= 1.0f) {
      float2 lg = logits[idx];
      l0 = lg.x; l1 = lg.y;
      r0 = rb.x; r1 = rb.y; r2 = rb.z; r3 = rb.w;
      lvf = (float)lvl; vf = 1.0f;
    }
  }
  out[2 * r] = l0;
  out[2 * r + 1] = l1;
  out[2 * NPOST + 4 * r + 0] = r0;
  out[2 * NPOST + 4 * r + 1] = r1;
  out[2 * NPOST + 4 * r + 2] = r2;
  out[2 * NPOST + 4 * r + 3] = r3;
  out[6 * NPOST + r] = lvf;
  out[7 * NPOST + r] = vf;
}

extern "C" void kernel_launch(void* const* d_in, const int* in_sizes, int n_in,
                              void* d_out, int out_size, void* d_ws, size_t ws_size,
                              hipStream_t stream) {
  const float* logits = (const float*)d_in[0];
  const float* rois = (const float*)d_in[1];
  const int* levels = (const int*)d_in[2];
  int N = in_sizes[2];

  char* ws = (char*)d_ws;
  u32* sbits = (u32*)(ws + OFF_SBITS);
  u32* hist = (u32*)(ws + OFF_HIST);
  u32* ctrl = (u32*)(ws + OFF_CTRL);
  u32* tie = (u32*)(ws + OFF_TIE);
  u64* cand = (u64*)(ws + OFF_CAND);
  float4* shifted = (float4*)(ws + OFF_SHIFT);
  u32* keptpos = (u32*)(ws + OFF_KEPT);
  u64* mask = (u64*)(ws + OFF_MASK);

  hipMemsetAsync(ctrl, 0, 4096, stream);
  hipMemsetAsync(hist, 0, NLVL * 65536 * sizeof(u32), stream);

  int nb = (N + 255) / 256;
  k_score_hist<<<nb, 256, 0, stream>>>((const float2*)logits, levels, sbits, hist, N);
  k_scan_hi<<<NLVL, 256, 0, stream>>>(hist, ctrl);
  hipMemsetAsync(hist, 0, NLVL * 65536 * sizeof(u32), stream);
  k_hist_lo<<<nb, 256, 0, stream>>>(sbits, levels, ctrl, hist, N);
  k_scan_lo<<<NLVL, 256, 0, stream>>>(hist, ctrl);
  k_compact<<<nb, 256, 0, stream>>>(sbits, levels, (const float4*)rois, ctrl, cand, tie, N);
  k_ties<<<NLVL, 256, 0, stream>>>((const float4*)rois, ctrl, cand, tie);
  k_sort<<<1, 1024, 0, stream>>>(cand, ctrl);
  k_shift<<<(KPAD + 255) / 256, 256, 0, stream>>>(cand, (const float4*)rois, ctrl, shifted);
  if (ws_size >= WS_NEED) {
    dim3 g(KPAD / 64, KPAD / 64);   // 128x128 grid; rows/cols >= total are zero boxes
    k_build<<<g, 64, 0, stream>>>((const float4*)shifted, mask);
    k_scan<<<1, 64, 0, stream>>>(mask, ctrl, keptpos);
  } else {
    k_nms<<<1, 1024, 0, stream>>>(shifted, ctrl, keptpos);
  }
  k_out<<<(NPOST + 255) / 256, 256, 0, stream>>>(cand, keptpos, ctrl, (const float2*)logits,
                                                 (const float4*)rois, (float*)d_out);
}